// Round 17
// baseline (788.180 us; speedup 1.0000x reference)
//
#include <hip/hip_runtime.h>
#include <hip/hip_bf16.h>

#define T_STEPS 512
#define BATCH   2048
#define ISZ     128
#define HSZ     64
#define VSZ     128
#define ZSZ     192   // I + H

#define MBLK    8     // batch rows per block -> 256 blocks
#define ATHREADS 768  // wv0 = P, wv1-3 idle, wv4-7 = X, wv8-11 = O

typedef __attribute__((ext_vector_type(8))) short bf16x8;
typedef __attribute__((ext_vector_type(4))) float f32x4;
typedef __attribute__((ext_vector_type(2))) float f32x2;
typedef __attribute__((ext_vector_type(4))) unsigned short u16x4;
typedef __attribute__((ext_vector_type(2))) unsigned short u16x2;

__device__ __forceinline__ unsigned short f2bf(float x) {
  union { float f; unsigned int u; } v; v.f = x;
  unsigned int u = v.u;
  unsigned int r = (u + 0x7fffu + ((u >> 16) & 1u)) >> 16;  // RNE
  return (unsigned short)r;
}

__device__ __forceinline__ unsigned short f2bf_hw(float x) {
  __hip_bfloat16 b = __float2bfloat16(x);
  return *reinterpret_cast<unsigned short*>(&b);
}

// branch-free, NaN-safe at +/-inf (validated rounds 8-16)
__device__ __forceinline__ float fsig(float x) {
  float e = __expf(-x);
  return __builtin_amdgcn_rcpf(1.0f + e);
}
__device__ __forceinline__ float ftanh2(float x) {
  float e = __expf(-2.0f * x);
  return __builtin_amdgcn_rcpf(1.0f + e) * 2.0f - 1.0f;
}

__device__ __forceinline__ void stage16(const void* g, void* l) {
  __builtin_amdgcn_global_load_lds(
      (const __attribute__((address_space(1))) void*)g,
      (__attribute__((address_space(3))) void*)l, 16, 0, 0);
}

// == Fused: P (single-wave h-chain) + X (DMA + x-GEMM) + O (out-proj/softmax) ==
__global__ __launch_bounds__(ATHREADS, 1) void lstm_fused(
    const float* __restrict__ x,
    const float* __restrict__ h0,
    const float* __restrict__ c0,
    const float* __restrict__ Wf,  const float* __restrict__ bf_,
    const float* __restrict__ Wif, const float* __restrict__ bif_,
    const float* __restrict__ Wic, const float* __restrict__ bic_,
    const float* __restrict__ Wo,  const float* __restrict__ bo_,
    const float* __restrict__ Wout, const float* __restrict__ bout_,
    float* __restrict__ out)
{
  // gbuf[slot4][xw4][(g*4+lkg)16][col8(batch)][4e] f32 C-frags; 64KB
  __shared__ __attribute__((aligned(16))) float gbuf[4][4][1024];
  // xbuf: 5-slot ring of x tiles [8 rows][512B], swizzled content; 20KB
  __shared__ __attribute__((aligned(16))) float xbuf[5][1024];
  // hbuf: 8-slot ring [16 rows][64 cols] bf16, XOR-swizzled; 16KB
  __shared__ __attribute__((aligned(16))) unsigned short hbuf[8 * 16 * 64];
  // Wh A-fragments, lane-contiguous: [(mt*2+kf)][lane] x 16B; 32KB
  __shared__ __attribute__((aligned(16))) unsigned short whA[32 * 64 * 8];

  const int tid  = threadIdx.x;
  const int wv   = tid >> 6;     // 0 = P, 1-3 idle, 4-7 = X, 8-11 = O
  const int ln   = tid & 63;
  const int lrow = ln & 15;
  const int lkg  = ln >> 4;
  const int b0   = blockIdx.x * MBLK;
  const int swz  = (lrow & 7) << 4;

  const float* Wg_[4] = {Wf, Wif, Wic, Wo};
  const float* bg_[4] = {bf_, bif_, bic_, bo_};

  // zero hbuf (rows 8..15 of every slot stay zero forever)
  for (int i = tid; i < 8 * 16 * 64; i += ATHREADS) hbuf[i] = 0;
  __syncthreads();
  if (tid < 128) {   // stage h0 into slot 0, rows 0..7, swizzled b64
    const int r = tid >> 4, cb = tid & 15;
    f32x4 hv = *(const f32x4*)&h0[(b0 + r) * HSZ + cb * 4];
    u16x4 pk;
#pragma unroll
    for (int j = 0; j < 4; ++j) pk[j] = f2bf(hv[j]);
    *(u16x4*)((char*)hbuf + r * 128 + ((cb * 8) ^ ((r & 7) << 4))) = pk;
  }
  // stage Wh A-fragments (waves 0-3, 8 (mt,kf) combos each)
  if (wv < 4) {
#pragma unroll
    for (int q = 0; q < 8; ++q) {
      const int c  = wv * 8 + q;        // 0..31
      const int mt = c >> 1, kf = c & 1;
      const int g  = mt >> 2, m4 = mt & 3;
      const float* p = Wg_[g] + (m4 * 16 + lrow) * ZSZ + ISZ + kf * 32 + 8 * lkg;
      bf16x8 f;
#pragma unroll
      for (int e = 0; e < 8; ++e) f[e] = (short)f2bf(p[e]);
      *(bf16x8*)&whA[(c * 64 + ln) * 8] = f;
    }
  }

  const size_t probs_elems = (size_t)T_STEPS * BATCH * VSZ;

  if (wv == 0) {
    // ========== P-wave: single-wave recurrence, no cross-wave exchange ======
    const int hi = lrow >> 3;     // 0: cells e=0,1   1: cells e=2,3
    float cst[4][2], hh[4][2];
#pragma unroll
    for (int mp = 0; mp < 4; ++mp)
#pragma unroll
      for (int j = 0; j < 2; ++j)
        cst[mp][j] = c0[(b0 + (lrow & 7)) * HSZ + 16 * mp + 4 * lkg + 2 * hi + j];

    __builtin_amdgcn_s_setprio(1);
    __syncthreads();   // (B): X produced g[0], g[1]; whA/h0 staged

    for (int t = 0; t < T_STEPS; ++t) {
      __builtin_amdgcn_s_barrier();
      asm volatile("" ::: "memory");

      // h[t] B-fragments (rows 8-15 are zeros -> zero B cols for junk batch)
      const char* hbase = (const char*)hbuf + (t & 7) * 2048 + lrow * 128;
      const bf16x8 hB0 = *(const bf16x8*)(hbase + ((lkg * 16) ^ swz));
      const bf16x8 hB1 = *(const bf16x8*)(hbase + ((64 + lkg * 16) ^ swz));

      // 16 M-tiles x 2 kf: full 256-gatecol h-GEMM in one wave
      f32x4 cur[16];
#pragma unroll
      for (int mt = 0; mt < 16; ++mt) {
        f32x4 a = *(const f32x4*)&gbuf[t & 3][mt & 3]
                       [((mt >> 2) * 4 + lkg) * 64 + lrow * 4];
        const bf16x8 A0 = *(const bf16x8*)&whA[((mt * 2 + 0) * 64 + ln) * 8];
        const bf16x8 A1 = *(const bf16x8*)&whA[((mt * 2 + 1) * 64 + ln) * 8];
        a = __builtin_amdgcn_mfma_f32_16x16x32_bf16(A0, hB0, a, 0, 0, 0);
        cur[mt] = __builtin_amdgcn_mfma_f32_16x16x32_bf16(A1, hB1, a, 0, 0, 0);
      }

      // cell: spread e={2,3} to hi lanes (valid data pulled from lane-8),
      // 2 cells/lane on all 64 lanes
#pragma unroll
      for (int mp = 0; mp < 4; ++mp) {
        float gfv[4][2];
#pragma unroll
        for (int g = 0; g < 4; ++g) {
          const f32x4 cg = cur[g * 4 + mp];
          const float a2 = __shfl_xor(cg[2], 8);
          const float a3 = __shfl_xor(cg[3], 8);
          gfv[g][0] = hi ? a2 : cg[0];
          gfv[g][1] = hi ? a3 : cg[1];
        }
        u16x2 pk;
#pragma unroll
        for (int j = 0; j < 2; ++j) {
          const float fg = fsig(gfv[0][j]);
          const float ig = fsig(gfv[1][j]);
          const float cd = ftanh2(gfv[2][j]);
          const float og = fsig(gfv[3][j]);
          const float c  = cst[mp][j] * fg + cd * ig;
          cst[mp][j] = c;
          hh[mp][j] = ftanh2(c) * og;
          pk[j] = f2bf_hw(hh[mp][j]);
        }
        // publish h[t+1]: b32 swizzled LDS write (col = 16mp+4lkg+2hi)
        *(u16x2*)((char*)hbuf + ((t + 1) & 7) * 2048 + (lrow & 7) * 128 +
                  (((16 * mp + 4 * lkg + 2 * hi) * 2) ^ swz)) = pk;
      }

      asm volatile("s_waitcnt lgkmcnt(0)" ::: "memory");
    }

    __builtin_amdgcn_s_barrier();   // final
    // final h/c outputs (lane's 8 cells)
#pragma unroll
    for (int mp = 0; mp < 4; ++mp) {
      const int cc = 16 * mp + 4 * lkg + 2 * hi;
      f32x2 hv = {hh[mp][0], hh[mp][1]};
      f32x2 cv = {cst[mp][0], cst[mp][1]};
      *(f32x2*)&out[probs_elems + (size_t)(b0 + (lrow & 7)) * HSZ + cc] = hv;
      *(f32x2*)&out[probs_elems + (size_t)BATCH * HSZ +
                    (size_t)(b0 + (lrow & 7)) * HSZ + cc] = cv;
    }
  } else if (wv < 4) {
    // ========== idle waves: barrier-matching only ==========
    __syncthreads();   // (B)
    for (int t = 0; t < T_STEPS; ++t) {
      __builtin_amdgcn_s_barrier();
    }
    __builtin_amdgcn_s_barrier();   // final
  } else if (wv < 8) {
    // ========== X-wave: DMA x + time-packed x-GEMM (r16 verbatim) ===========
    const int xw = wv - 4;
    const int hcolX = 16 * xw + lrow;

    bf16x8 fragWx[4][4];
#pragma unroll
    for (int g = 0; g < 4; ++g)
#pragma unroll
      for (int kf = 0; kf < 4; ++kf) {
        const float* p = Wg_[g] + hcolX * ZSZ + kf * 32 + 8 * lkg;
        bf16x8 f;
#pragma unroll
        for (int e = 0; e < 8; ++e) f[e] = (short)f2bf(p[e]);
        fragWx[g][kf] = f;
      }
    f32x4 biasV[4];
#pragma unroll
    for (int g = 0; g < 4; ++g)
      biasV[g] = *(const f32x4*)&bg_[g][16 * xw + 4 * lkg];

#define STAGE(TT, SLOT)                                                        \
    {                                                                          \
      const int tc = ((TT) < T_STEPS) ? (TT) : T_STEPS - 1;                    \
      const char* xb = (const char*)(x + (size_t)tc * BATCH * ISZ +            \
                                     (size_t)b0 * ISZ);                        \
      char* lb = (char*)&xbuf[SLOT][0];                                        \
      _Pragma("unroll")                                                        \
      for (int i = 0; i < 4; ++i) {                                            \
        const int row = 2 * i + (ln >> 5);                                     \
        const int sc = ((ln & 31) * 16) ^ ((row & 7) << 4);                    \
        stage16(xb + row * 512 + sc, lb + i * 1024);                           \
      }                                                                        \
    }

#define XPAIR(SE, SO, GE, GO)                                                  \
    {                                                                          \
      const char* xt = (const char*)&xbuf[(lrow & 8) ? (SO) : (SE)][0] +       \
                       (lrow & 7) * 512;                                       \
      f32x4 xacc[4];                                                           \
      _Pragma("unroll")                                                        \
      for (int g = 0; g < 4; ++g) xacc[g] = biasV[g];                          \
      _Pragma("unroll")                                                        \
      for (int kf = 0; kf < 4; ++kf) {                                         \
        const int cb = kf * 128 + lkg * 32;                                    \
        f32x4 a = *(const f32x4*)(xt + ((cb) ^ swz));                          \
        f32x4 b = *(const f32x4*)(xt + ((cb + 16) ^ swz));                     \
        bf16x8 f;                                                              \
        _Pragma("unroll")                                                      \
        for (int j = 0; j < 4; ++j) {                                          \
          f[j]     = (short)f2bf_hw(a[j]);                                     \
          f[4 + j] = (short)f2bf_hw(b[j]);                                     \
        }                                                                      \
        _Pragma("unroll")                                                      \
        for (int g = 0; g < 4; ++g)                                            \
          xacc[g] = __builtin_amdgcn_mfma_f32_16x16x32_bf16(                   \
              fragWx[g][kf], f, xacc[g], 0, 0, 0);                             \
      }                                                                        \
      float* gdst = (lrow & 8) ? &gbuf[GO][xw][0] : &gbuf[GE][xw][0];          \
      _Pragma("unroll")                                                        \
      for (int g = 0; g < 4; ++g)                                              \
        *(f32x4*)&gdst[(g * 4 + lkg) * 64 + (lrow & 7) * 4] = xacc[g];         \
    }

    // prologue: stage tiles 0..4; produce g[0], g[1]
    STAGE(0, 0) STAGE(1, 1) STAGE(2, 2) STAGE(3, 3) STAGE(4, 4)
    asm volatile("s_waitcnt vmcnt(12)" ::: "memory");   // tiles 0,1 landed
    __builtin_amdgcn_sched_barrier(0);
    XPAIR(0, 1, 0, 1)
    asm volatile("s_waitcnt lgkmcnt(0)" ::: "memory");
    __syncthreads();   // (B)

    int stg = 0;   // xbuf slot staged this round
    int rs  = 2;   // xbuf slot holding tile t+2 at even-round top
    int gw  = 2;   // gbuf slot for g[t+2]
    for (int t = 0; t < T_STEPS; t += 2) {
      // even round: stage + produce pair (t+2, t+3)
      __builtin_amdgcn_s_barrier();
      asm volatile("" ::: "memory");
      STAGE(t + 5, stg)
      stg = (stg == 4) ? 0 : stg + 1;
      asm volatile("s_waitcnt vmcnt(8)" ::: "memory");  // tiles t+2,t+3 landed
      __builtin_amdgcn_sched_barrier(0);
      {
        const int rs1 = (rs == 4) ? 0 : rs + 1;
        XPAIR(rs, rs1, gw, (gw + 1) & 3)
        rs = (rs1 == 4) ? 0 : rs1 + 1;
        gw = (gw + 2) & 3;
      }
      asm volatile("s_waitcnt lgkmcnt(0)" ::: "memory");

      // odd round: stage only
      __builtin_amdgcn_s_barrier();
      asm volatile("" ::: "memory");
      STAGE(t + 6, stg)
      stg = (stg == 4) ? 0 : stg + 1;
    }
    __builtin_amdgcn_s_barrier();   // final
#undef XPAIR
#undef STAGE
  } else {
    // ========== O-wave: out-proj + softmax + probs store (r16 verbatim) ======
    const int o = wv - 8;

    bf16x8 fragWo[8][2];
#pragma unroll
    for (int rf = 0; rf < 8; ++rf)
#pragma unroll
      for (int kf = 0; kf < 2; ++kf) {
        const float* p = Wout + (16 * rf + lrow) * HSZ + kf * 32 + 8 * lkg;
        bf16x8 f;
#pragma unroll
        for (int e = 0; e < 8; ++e) f[e] = (short)f2bf(p[e]);
        fragWo[rf][kf] = f;
      }
    f32x4 boV[8];
#pragma unroll
    for (int rf = 0; rf < 8; ++rf) boV[rf] = *(const f32x4*)&bout_[16 * rf + 4 * lkg];

    __syncthreads();   // (B)

    f32x4 lac[8];
    bf16x8 hO0, hO1;
    float inv = 0.0f;

    for (int e = 0; e < 128; ++e) {
      const int tau = 4 * (e - 1) + 1 + o;
      const bool act = (e > 0);

      __builtin_amdgcn_s_barrier();
      asm volatile("" ::: "memory");
      if (act) {
        const char* hb = (const char*)hbuf + (tau & 7) * 2048 + lrow * 128;
        hO0 = *(const bf16x8*)(hb + ((lkg * 16) ^ swz));
        hO1 = *(const bf16x8*)(hb + ((64 + lkg * 16) ^ swz));
#pragma unroll
        for (int rf = 0; rf < 4; ++rf) {
          lac[rf] = boV[rf];
          lac[rf] = __builtin_amdgcn_mfma_f32_16x16x32_bf16(fragWo[rf][0], hO0, lac[rf], 0, 0, 0);
          lac[rf] = __builtin_amdgcn_mfma_f32_16x16x32_bf16(fragWo[rf][1], hO1, lac[rf], 0, 0, 0);
        }
      }

      __builtin_amdgcn_s_barrier();
      asm volatile("" ::: "memory");
      if (act) {
#pragma unroll
        for (int rf = 4; rf < 8; ++rf) {
          lac[rf] = boV[rf];
          lac[rf] = __builtin_amdgcn_mfma_f32_16x16x32_bf16(fragWo[rf][0], hO0, lac[rf], 0, 0, 0);
          lac[rf] = __builtin_amdgcn_mfma_f32_16x16x32_bf16(fragWo[rf][1], hO1, lac[rf], 0, 0, 0);
        }
      }

      __builtin_amdgcn_s_barrier();
      asm volatile("" ::: "memory");
      if (act) {
        float m = -1e30f;
#pragma unroll
        for (int rf = 0; rf < 8; ++rf)
#pragma unroll
          for (int e2 = 0; e2 < 4; ++e2) m = fmaxf(m, lac[rf][e2]);
        m = fmaxf(m, __shfl_xor(m, 16));
        m = fmaxf(m, __shfl_xor(m, 32));
        float s = 0.0f;
#pragma unroll
        for (int rf = 0; rf < 8; ++rf)
#pragma unroll
          for (int e2 = 0; e2 < 4; ++e2) {
            float p = __expf(lac[rf][e2] - m);
            lac[rf][e2] = p;
            s += p;
          }
        s += __shfl_xor(s, 16);
        s += __shfl_xor(s, 32);
        inv = 1.0f / s;
      }

      __builtin_amdgcn_s_barrier();
      asm volatile("" ::: "memory");
      if (act && lrow < MBLK) {
        float* orow = &out[(size_t)(tau - 1) * BATCH * VSZ +
                           (size_t)(b0 + lrow) * VSZ];
#pragma unroll
        for (int rf = 0; rf < 8; ++rf) {
          f32x4 pv = lac[rf] * inv;
          *(f32x4*)&orow[16 * rf + 4 * lkg] = pv;
        }
      }
    }

    __builtin_amdgcn_s_barrier();   // final
    {
      const int tau = T_STEPS - 3 + o;
      const char* hb = (const char*)hbuf + (tau & 7) * 2048 + lrow * 128;
      const bf16x8 ha = *(const bf16x8*)(hb + ((lkg * 16) ^ swz));
      const bf16x8 hbv = *(const bf16x8*)(hb + ((64 + lkg * 16) ^ swz));
#pragma unroll
      for (int rf = 0; rf < 8; ++rf) {
        lac[rf] = boV[rf];
        lac[rf] = __builtin_amdgcn_mfma_f32_16x16x32_bf16(fragWo[rf][0], ha, lac[rf], 0, 0, 0);
        lac[rf] = __builtin_amdgcn_mfma_f32_16x16x32_bf16(fragWo[rf][1], hbv, lac[rf], 0, 0, 0);
      }
      float m = -1e30f;
#pragma unroll
      for (int rf = 0; rf < 8; ++rf)
#pragma unroll
        for (int e2 = 0; e2 < 4; ++e2) m = fmaxf(m, lac[rf][e2]);
      m = fmaxf(m, __shfl_xor(m, 16));
      m = fmaxf(m, __shfl_xor(m, 32));
      float s = 0.0f;
#pragma unroll
      for (int rf = 0; rf < 8; ++rf)
#pragma unroll
        for (int e2 = 0; e2 < 4; ++e2) {
          float p = __expf(lac[rf][e2] - m);
          lac[rf][e2] = p;
          s += p;
        }
      s += __shfl_xor(s, 16);
      s += __shfl_xor(s, 32);
      inv = 1.0f / s;
      if (lrow < MBLK) {
        float* orow = &out[(size_t)(tau - 1) * BATCH * VSZ +
                           (size_t)(b0 + lrow) * VSZ];
#pragma unroll
        for (int rf = 0; rf < 8; ++rf) {
          f32x4 pv = lac[rf] * inv;
          *(f32x4*)&orow[16 * rf + 4 * lkg] = pv;
        }
      }
    }
  }
}

extern "C" void kernel_launch(void* const* d_in, const int* in_sizes, int n_in,
                              void* d_out, int out_size, void* d_ws, size_t ws_size,
                              hipStream_t stream) {
  const float* x    = (const float*)d_in[0];
  const float* h0   = (const float*)d_in[1];
  const float* c0   = (const float*)d_in[2];
  const float* Wf   = (const float*)d_in[3];
  const float* bf_  = (const float*)d_in[4];
  const float* Wif  = (const float*)d_in[5];
  const float* bif_ = (const float*)d_in[6];
  const float* Wic  = (const float*)d_in[7];
  const float* bic_ = (const float*)d_in[8];
  const float* Wo   = (const float*)d_in[9];
  const float* bo_  = (const float*)d_in[10];
  const float* Wout = (const float*)d_in[11];
  const float* bout = (const float*)d_in[12];
  float* out = (float*)d_out;

  hipLaunchKernelGGL(lstm_fused, dim3(BATCH / MBLK), dim3(ATHREADS), 0, stream,
                     x, h0, c0, Wf, bf_, Wif, bif_, Wic, bic_, Wo, bo_,
                     Wout, bout, out);
}

// Round 18
// 509.829 us; speedup vs baseline: 1.5460x; 1.5460x over previous
//
#include <hip/hip_runtime.h>
#include <hip/hip_bf16.h>

#define T_STEPS 512
#define BATCH   2048
#define ISZ     128
#define HSZ     64
#define VSZ     128
#define ZSZ     192   // I + H

#define MBLK    8     // batch rows per block -> 256 blocks
#define ATHREADS 768  // 4 P + 4 X + 4 O waves (1P+1X+1O per SIMD)

typedef __attribute__((ext_vector_type(8))) short bf16x8;
typedef __attribute__((ext_vector_type(4))) float f32x4;
typedef __attribute__((ext_vector_type(2))) float f32x2;
typedef __attribute__((ext_vector_type(4))) unsigned short u16x4;
typedef __attribute__((ext_vector_type(2))) unsigned short u16x2;

__device__ __forceinline__ unsigned short f2bf(float x) {
  union { float f; unsigned int u; } v; v.f = x;
  unsigned int u = v.u;
  unsigned int r = (u + 0x7fffu + ((u >> 16) & 1u)) >> 16;  // RNE
  return (unsigned short)r;
}

__device__ __forceinline__ unsigned short f2bf_hw(float x) {
  __hip_bfloat16 b = __float2bfloat16(x);
  return *reinterpret_cast<unsigned short*>(&b);
}

// branch-free, NaN-safe at +/-inf (validated rounds 8-16)
__device__ __forceinline__ float fsig(float x) {
  float e = __expf(-x);
  return __builtin_amdgcn_rcpf(1.0f + e);
}
__device__ __forceinline__ float ftanh2(float x) {
  float e = __expf(-2.0f * x);
  return __builtin_amdgcn_rcpf(1.0f + e) * 2.0f - 1.0f;
}

__device__ __forceinline__ void stage16(const void* g, void* l) {
  __builtin_amdgcn_global_load_lds(
      (const __attribute__((address_space(1))) void*)g,
      (__attribute__((address_space(3))) void*)l, 16, 0, 0);
}

// ==== Fully fused: P (h-chain) + X (DMA + x-GEMM) + O (out-proj/softmax) =====
__global__ __launch_bounds__(ATHREADS, 1) void lstm_fused(
    const float* __restrict__ x,
    const float* __restrict__ h0,
    const float* __restrict__ c0,
    const float* __restrict__ Wf,  const float* __restrict__ bf_,
    const float* __restrict__ Wif, const float* __restrict__ bif_,
    const float* __restrict__ Wic, const float* __restrict__ bic_,
    const float* __restrict__ Wo,  const float* __restrict__ bo_,
    const float* __restrict__ Wout, const float* __restrict__ bout_,
    float* __restrict__ out)
{
  // gbuf: conflict-free stride (256B per (g*4+lkg) row); 64KB
  __shared__ __attribute__((aligned(16))) float gbuf[4][4][1024];
  // xbuf: 5-slot ring of x tiles [8 rows][512B], swizzled content; 20KB
  __shared__ __attribute__((aligned(16))) float xbuf[5][1024];
  // hbuf: 8-slot ring [16 rows][64 cols] bf16, XOR-swizzled; 16KB
  __shared__ __attribute__((aligned(16))) unsigned short hbuf[8 * 16 * 64];

  const int tid  = threadIdx.x;
  const int wv   = tid >> 6;     // 0..3 = P, 4..7 = X, 8..11 = O
  const int ln   = tid & 63;
  const int lrow = ln & 15;
  const int lkg  = ln >> 4;
  const int b0   = blockIdx.x * MBLK;
  const int swz  = (lrow & 7) << 4;

  // zero hbuf (rows 8..15 of every slot stay zero forever)
  for (int i = tid; i < 8 * 16 * 64; i += ATHREADS) hbuf[i] = 0;
  __syncthreads();
  if (tid < 128) {   // stage h0 into slot 0, rows 0..7, swizzled b64
    const int r = tid >> 4, cb = tid & 15;
    f32x4 hv = *(const f32x4*)&h0[(b0 + r) * HSZ + cb * 4];
    u16x4 pk;
#pragma unroll
    for (int j = 0; j < 4; ++j) pk[j] = f2bf(hv[j]);
    *(u16x4*)((char*)hbuf + r * 128 + ((cb * 8) ^ ((r & 7) << 4))) = pk;
  }

  const float* Wg_[4] = {Wf, Wif, Wic, Wo};
  const float* bg_[4] = {bf_, bif_, bic_, bo_};
  const size_t probs_elems = (size_t)T_STEPS * BATCH * VSZ;

  if (wv < 4) {
    // ========== P-wave: minimal h-chain + spread cell (all 64 lanes) ========
    const int hcol = 16 * wv + lrow;

    bf16x8 fragWh[4][2];
#pragma unroll
    for (int g = 0; g < 4; ++g)
#pragma unroll
      for (int kf = 0; kf < 2; ++kf) {
        const float* p = Wg_[g] + hcol * ZSZ + ISZ + kf * 32 + 8 * lkg;
        bf16x8 f;
#pragma unroll
        for (int e = 0; e < 8; ++e) f[e] = (short)f2bf(p[e]);
        fragWh[g][kf] = f;
      }

    // spread cell: lane(lkg,lrow) owns batch row (lrow&7),
    // hcols 16wv+4lkg+2hi+{0,1}  (hi = lrow>>3)
    const int hi   = lrow >> 3;
    const int brow = lrow & 7;
    const int eb   = 2 * hi;
    float cst[2], hh[2];
#pragma unroll
    for (int j = 0; j < 2; ++j)
      cst[j] = c0[(b0 + brow) * HSZ + 16 * wv + 4 * lkg + eb + j];

    __builtin_amdgcn_s_setprio(1);
    __syncthreads();   // (B): X produced g[0], g[1]

    f32x4 acc[4];
    {
      const float* gs = &gbuf[0][wv][0];
#pragma unroll
      for (int g = 0; g < 4; ++g)
        acc[g] = *(const f32x4*)&gs[(g * 4 + lkg) * 64 + lrow * 4];
    }

    for (int t = 0; t < T_STEPS; ++t) {
      __builtin_amdgcn_s_barrier();
      asm volatile("" ::: "memory");

      const char* hbase = (const char*)hbuf + (t & 7) * 2048 + lrow * 128;
      const bf16x8 hB0 = *(const bf16x8*)(hbase + ((lkg * 16) ^ swz));
      const bf16x8 hB1 = *(const bf16x8*)(hbase + ((64 + lkg * 16) ^ swz));

      f32x4 cur[4];
#pragma unroll
      for (int g = 0; g < 4; ++g)
        cur[g] = __builtin_amdgcn_mfma_f32_16x16x32_bf16(fragWh[g][0], hB0, acc[g], 0, 0, 0);
#pragma unroll
      for (int g = 0; g < 4; ++g)
        cur[g] = __builtin_amdgcn_mfma_f32_16x16x32_bf16(fragWh[g][1], hB1, cur[g], 0, 0, 0);

      // preload next round's x-part acc (written by X >=1 barrier ago)
      {
        const float* gs = &gbuf[(t + 1) & 3][wv][0];
#pragma unroll
        for (int g = 0; g < 4; ++g)
          acc[g] = *(const f32x4*)&gs[(g * 4 + lkg) * 64 + lrow * 4];
      }

      // spread: hi-lanes take e={2,3} of partner (lane^8); 2 cells/lane,
      // all 64 lanes active -> 20 trans/lane instead of 40 on half-wave
      float ga[4][2];
#pragma unroll
      for (int g = 0; g < 4; ++g) {
        const float a2 = __shfl_xor(cur[g][2], 8);
        const float a3 = __shfl_xor(cur[g][3], 8);
        ga[g][0] = hi ? a2 : cur[g][0];
        ga[g][1] = hi ? a3 : cur[g][1];
      }

      u16x2 pk;
#pragma unroll
      for (int j = 0; j < 2; ++j) {
        const float fg = fsig(ga[0][j]);
        const float ig = fsig(ga[1][j]);
        const float cd = ftanh2(ga[2][j]);
        const float og = fsig(ga[3][j]);
        const float c  = cst[j] * fg + cd * ig;
        cst[j] = c;
        hh[j] = ftanh2(c) * og;
        pk[j] = f2bf_hw(hh[j]);
      }

      // publish h[t+1]: b32 swizzled LDS write (col = 16wv+4lkg+2hi)
      *(u16x2*)((char*)hbuf + ((t + 1) & 7) * 2048 + brow * 128 +
                (((16 * wv + 4 * lkg + eb) * 2) ^ ((brow & 7) << 4))) = pk;

      asm volatile("s_waitcnt lgkmcnt(0)" ::: "memory");
    }

    __builtin_amdgcn_s_barrier();   // final (matches X/O epilogue)
    {
      const int cc = 16 * wv + 4 * lkg + eb;
      f32x2 hv = {hh[0], hh[1]}, cv = {cst[0], cst[1]};
      *(f32x2*)&out[probs_elems + (size_t)(b0 + brow) * HSZ + cc] = hv;
      *(f32x2*)&out[probs_elems + (size_t)BATCH * HSZ +
                    (size_t)(b0 + brow) * HSZ + cc] = cv;
    }
  } else if (wv < 8) {
    // ========== X-wave: DMA x + time-packed x-GEMM (r16 verbatim) ===========
    const int xw = wv - 4;
    const int hcolX = 16 * xw + lrow;

    bf16x8 fragWx[4][4];
#pragma unroll
    for (int g = 0; g < 4; ++g)
#pragma unroll
      for (int kf = 0; kf < 4; ++kf) {
        const float* p = Wg_[g] + hcolX * ZSZ + kf * 32 + 8 * lkg;
        bf16x8 f;
#pragma unroll
        for (int e = 0; e < 8; ++e) f[e] = (short)f2bf(p[e]);
        fragWx[g][kf] = f;
      }
    f32x4 biasV[4];
#pragma unroll
    for (int g = 0; g < 4; ++g)
      biasV[g] = *(const f32x4*)&bg_[g][16 * xw + 4 * lkg];

#define STAGE(TT, SLOT)                                                        \
    {                                                                          \
      const int tc = ((TT) < T_STEPS) ? (TT) : T_STEPS - 1;                    \
      const char* xb = (const char*)(x + (size_t)tc * BATCH * ISZ +            \
                                     (size_t)b0 * ISZ);                        \
      char* lb = (char*)&xbuf[SLOT][0];                                        \
      _Pragma("unroll")                                                        \
      for (int i = 0; i < 4; ++i) {                                            \
        const int row = 2 * i + (ln >> 5);                                     \
        const int sc = ((ln & 31) * 16) ^ ((row & 7) << 4);                    \
        stage16(xb + row * 512 + sc, lb + i * 1024);                           \
      }                                                                        \
    }

#define XPAIR(SE, SO, GE, GO)                                                  \
    {                                                                          \
      const char* xt = (const char*)&xbuf[(lrow & 8) ? (SO) : (SE)][0] +       \
                       (lrow & 7) * 512;                                       \
      f32x4 xacc[4];                                                           \
      _Pragma("unroll")                                                        \
      for (int g = 0; g < 4; ++g) xacc[g] = biasV[g];                          \
      _Pragma("unroll")                                                        \
      for (int kf = 0; kf < 4; ++kf) {                                         \
        const int cb = kf * 128 + lkg * 32;                                    \
        f32x4 a = *(const f32x4*)(xt + ((cb) ^ swz));                          \
        f32x4 b = *(const f32x4*)(xt + ((cb + 16) ^ swz));                     \
        bf16x8 f;                                                              \
        _Pragma("unroll")                                                      \
        for (int j = 0; j < 4; ++j) {                                          \
          f[j]     = (short)f2bf_hw(a[j]);                                     \
          f[4 + j] = (short)f2bf_hw(b[j]);                                     \
        }                                                                      \
        _Pragma("unroll")                                                      \
        for (int g = 0; g < 4; ++g)                                            \
          xacc[g] = __builtin_amdgcn_mfma_f32_16x16x32_bf16(                   \
              fragWx[g][kf], f, xacc[g], 0, 0, 0);                             \
      }                                                                        \
      float* gdst = (lrow & 8) ? &gbuf[GO][xw][0] : &gbuf[GE][xw][0];          \
      _Pragma("unroll")                                                        \
      for (int g = 0; g < 4; ++g)                                              \
        *(f32x4*)&gdst[(g * 4 + lkg) * 64 + (lrow & 7) * 4] = xacc[g];         \
    }

    // prologue: stage tiles 0..4; produce g[0], g[1]
    STAGE(0, 0) STAGE(1, 1) STAGE(2, 2) STAGE(3, 3) STAGE(4, 4)
    asm volatile("s_waitcnt vmcnt(12)" ::: "memory");   // tiles 0,1 landed
    __builtin_amdgcn_sched_barrier(0);
    XPAIR(0, 1, 0, 1)
    asm volatile("s_waitcnt lgkmcnt(0)" ::: "memory");
    __syncthreads();   // (B)

    int stg = 0;   // xbuf slot staged this round
    int rs  = 2;   // xbuf slot holding tile t+2 at even-round top
    int gw  = 2;   // gbuf slot for g[t+2]
    for (int t = 0; t < T_STEPS; t += 2) {
      // even round: stage + produce pair (t+2, t+3)
      __builtin_amdgcn_s_barrier();
      asm volatile("" ::: "memory");
      STAGE(t + 5, stg)
      stg = (stg == 4) ? 0 : stg + 1;
      asm volatile("s_waitcnt vmcnt(8)" ::: "memory");  // tiles t+2,t+3 landed
      __builtin_amdgcn_sched_barrier(0);
      {
        const int rs1 = (rs == 4) ? 0 : rs + 1;
        XPAIR(rs, rs1, gw, (gw + 1) & 3)
        rs = (rs1 == 4) ? 0 : rs1 + 1;
        gw = (gw + 2) & 3;
      }
      asm volatile("s_waitcnt lgkmcnt(0)" ::: "memory");

      // odd round: stage only
      __builtin_amdgcn_s_barrier();
      asm volatile("" ::: "memory");
      STAGE(t + 6, stg)
      stg = (stg == 4) ? 0 : stg + 1;
    }
    __builtin_amdgcn_s_barrier();   // final
#undef XPAIR
#undef STAGE
  } else {
    // ========== O-wave: out-proj + softmax + probs store (r16 verbatim) ======
    const int o = wv - 8;

    bf16x8 fragWo[8][2];
#pragma unroll
    for (int rf = 0; rf < 8; ++rf)
#pragma unroll
      for (int kf = 0; kf < 2; ++kf) {
        const float* p = Wout + (16 * rf + lrow) * HSZ + kf * 32 + 8 * lkg;
        bf16x8 f;
#pragma unroll
        for (int e = 0; e < 8; ++e) f[e] = (short)f2bf(p[e]);
        fragWo[rf][kf] = f;
      }
    f32x4 boV[8];
#pragma unroll
    for (int rf = 0; rf < 8; ++rf) boV[rf] = *(const f32x4*)&bout_[16 * rf + 4 * lkg];

    __syncthreads();   // (B)

    f32x4 lac[8];
    bf16x8 hO0, hO1;
    float inv = 0.0f;

    for (int e = 0; e < 128; ++e) {
      const int tau = 4 * (e - 1) + 1 + o;
      const bool act = (e > 0);

      __builtin_amdgcn_s_barrier();
      asm volatile("" ::: "memory");
      if (act) {
        const char* hb = (const char*)hbuf + (tau & 7) * 2048 + lrow * 128;
        hO0 = *(const bf16x8*)(hb + ((lkg * 16) ^ swz));
        hO1 = *(const bf16x8*)(hb + ((64 + lkg * 16) ^ swz));
#pragma unroll
        for (int rf = 0; rf < 4; ++rf) {
          lac[rf] = boV[rf];
          lac[rf] = __builtin_amdgcn_mfma_f32_16x16x32_bf16(fragWo[rf][0], hO0, lac[rf], 0, 0, 0);
          lac[rf] = __builtin_amdgcn_mfma_f32_16x16x32_bf16(fragWo[rf][1], hO1, lac[rf], 0, 0, 0);
        }
      }

      __builtin_amdgcn_s_barrier();
      asm volatile("" ::: "memory");
      if (act) {
#pragma unroll
        for (int rf = 4; rf < 8; ++rf) {
          lac[rf] = boV[rf];
          lac[rf] = __builtin_amdgcn_mfma_f32_16x16x32_bf16(fragWo[rf][0], hO0, lac[rf], 0, 0, 0);
          lac[rf] = __builtin_amdgcn_mfma_f32_16x16x32_bf16(fragWo[rf][1], hO1, lac[rf], 0, 0, 0);
        }
      }

      __builtin_amdgcn_s_barrier();
      asm volatile("" ::: "memory");
      if (act) {
        float m = -1e30f;
#pragma unroll
        for (int rf = 0; rf < 8; ++rf)
#pragma unroll
          for (int e2 = 0; e2 < 4; ++e2) m = fmaxf(m, lac[rf][e2]);
        m = fmaxf(m, __shfl_xor(m, 16));
        m = fmaxf(m, __shfl_xor(m, 32));
        float s = 0.0f;
#pragma unroll
        for (int rf = 0; rf < 8; ++rf)
#pragma unroll
          for (int e2 = 0; e2 < 4; ++e2) {
            float p = __expf(lac[rf][e2] - m);
            lac[rf][e2] = p;
            s += p;
          }
        s += __shfl_xor(s, 16);
        s += __shfl_xor(s, 32);
        inv = 1.0f / s;
      }

      __builtin_amdgcn_s_barrier();
      asm volatile("" ::: "memory");
      if (act && lrow < MBLK) {
        float* orow = &out[(size_t)(tau - 1) * BATCH * VSZ +
                           (size_t)(b0 + lrow) * VSZ];
#pragma unroll
        for (int rf = 0; rf < 8; ++rf) {
          f32x4 pv = lac[rf] * inv;
          *(f32x4*)&orow[16 * rf + 4 * lkg] = pv;
        }
      }
    }

    __builtin_amdgcn_s_barrier();   // final
    {
      const int tau = T_STEPS - 3 + o;
      const char* hb = (const char*)hbuf + (tau & 7) * 2048 + lrow * 128;
      const bf16x8 ha = *(const bf16x8*)(hb + ((lkg * 16) ^ swz));
      const bf16x8 hbv = *(const bf16x8*)(hb + ((64 + lkg * 16) ^ swz));
#pragma unroll
      for (int rf = 0; rf < 8; ++rf) {
        lac[rf] = boV[rf];
        lac[rf] = __builtin_amdgcn_mfma_f32_16x16x32_bf16(fragWo[rf][0], ha, lac[rf], 0, 0, 0);
        lac[rf] = __builtin_amdgcn_mfma_f32_16x16x32_bf16(fragWo[rf][1], hbv, lac[rf], 0, 0, 0);
      }
      float m = -1e30f;
#pragma unroll
      for (int rf = 0; rf < 8; ++rf)
#pragma unroll
        for (int e2 = 0; e2 < 4; ++e2) m = fmaxf(m, lac[rf][e2]);
      m = fmaxf(m, __shfl_xor(m, 16));
      m = fmaxf(m, __shfl_xor(m, 32));
      float s = 0.0f;
#pragma unroll
      for (int rf = 0; rf < 8; ++rf)
#pragma unroll
        for (int e2 = 0; e2 < 4; ++e2) {
          float p = __expf(lac[rf][e2] - m);
          lac[rf][e2] = p;
          s += p;
        }
      s += __shfl_xor(s, 16);
      s += __shfl_xor(s, 32);
      inv = 1.0f / s;
      if (lrow < MBLK) {
        float* orow = &out[(size_t)(tau - 1) * BATCH * VSZ +
                           (size_t)(b0 + lrow) * VSZ];
#pragma unroll
        for (int rf = 0; rf < 8; ++rf) {
          f32x4 pv = lac[rf] * inv;
          *(f32x4*)&orow[16 * rf + 4 * lkg] = pv;
        }
      }
    }
  }
}

extern "C" void kernel_launch(void* const* d_in, const int* in_sizes, int n_in,
                              void* d_out, int out_size, void* d_ws, size_t ws_size,
                              hipStream_t stream) {
  const float* x    = (const float*)d_in[0];
  const float* h0   = (const float*)d_in[1];
  const float* c0   = (const float*)d_in[2];
  const float* Wf   = (const float*)d_in[3];
  const float* bf_  = (const float*)d_in[4];
  const float* Wif  = (const float*)d_in[5];
  const float* bif_ = (const float*)d_in[6];
  const float* Wic  = (const float*)d_in[7];
  const float* bic_ = (const float*)d_in[8];
  const float* Wo   = (const float*)d_in[9];
  const float* bo_  = (const float*)d_in[10];
  const float* Wout = (const float*)d_in[11];
  const float* bout = (const float*)d_in[12];
  float* out = (float*)d_out;

  hipLaunchKernelGGL(lstm_fused, dim3(BATCH / MBLK), dim3(ATHREADS), 0, stream,
                     x, h0, c0, Wf, bf_, Wif, bif_, Wic, bic_, Wo, bo_,
                     Wout, bout, out);
}

// Round 20
// 371.937 us; speedup vs baseline: 2.1191x; 1.3707x over previous
//
#include <hip/hip_runtime.h>
#include <hip/hip_bf16.h>

#define T_STEPS 512
#define BATCH   2048
#define ISZ     128
#define HSZ     64
#define VSZ     128
#define ZSZ     192   // I + H

#define MBLK    8     // batch rows per block -> 256 blocks
#define ATHREADS 768  // 4 P + 4 X + 4 O waves (1P+1X+1O per SIMD)

typedef __attribute__((ext_vector_type(8))) short bf16x8;
typedef __attribute__((ext_vector_type(4))) float f32x4;
typedef __attribute__((ext_vector_type(4))) unsigned short u16x4;

__device__ __forceinline__ unsigned short f2bf(float x) {
  union { float f; unsigned int u; } v; v.f = x;
  unsigned int u = v.u;
  unsigned int r = (u + 0x7fffu + ((u >> 16) & 1u)) >> 16;  // RNE
  return (unsigned short)r;
}

__device__ __forceinline__ unsigned short f2bf_hw(float x) {
  __hip_bfloat16 b = __float2bfloat16(x);
  return *reinterpret_cast<unsigned short*>(&b);
}

// branch-free, NaN-safe at +/-inf (validated rounds 8-18)
__device__ __forceinline__ float fsig(float x) {
  float e = __expf(-x);
  return __builtin_amdgcn_rcpf(1.0f + e);
}
__device__ __forceinline__ float ftanh2(float x) {
  float e = __expf(-2.0f * x);
  return __builtin_amdgcn_rcpf(1.0f + e) * 2.0f - 1.0f;
}

// ==== Fused: P (h-chain) + X (reg-staged x-GEMM) + O (out-proj/softmax) ======
__global__ __launch_bounds__(ATHREADS, 1) void lstm_fused(
    const float* __restrict__ x,
    const float* __restrict__ h0,
    const float* __restrict__ c0,
    const float* __restrict__ Wf,  const float* __restrict__ bf_,
    const float* __restrict__ Wif, const float* __restrict__ bif_,
    const float* __restrict__ Wic, const float* __restrict__ bic_,
    const float* __restrict__ Wo,  const float* __restrict__ bo_,
    const float* __restrict__ Wout, const float* __restrict__ bout_,
    float* __restrict__ out)
{
  // gbuf: r16-verbatim f32 C-frag layout (256B per (g*4+lkg) row); 64KB
  __shared__ __attribute__((aligned(16))) float gbuf[4][4][1024];
  // hbuf: 8-slot ring [16 rows][64 cols] bf16, XOR-swizzled; 16KB
  __shared__ __attribute__((aligned(16))) unsigned short hbuf[8 * 16 * 64];

  const int tid  = threadIdx.x;
  const int wv   = tid >> 6;     // 0..3 = P, 4..7 = X, 8..11 = O
  const int ln   = tid & 63;
  const int lrow = ln & 15;
  const int lkg  = ln >> 4;
  const int b0   = blockIdx.x * MBLK;
  const int swz  = (lrow & 7) << 4;

  // zero hbuf (rows 8..15 of every slot stay zero forever)
  for (int i = tid; i < 8 * 16 * 64; i += ATHREADS) hbuf[i] = 0;
  __syncthreads();
  if (tid < 128) {   // stage h0 into slot 0, rows 0..7, swizzled b64
    const int r = tid >> 4, cb = tid & 15;
    f32x4 hv = *(const f32x4*)&h0[(b0 + r) * HSZ + cb * 4];
    u16x4 pk;
#pragma unroll
    for (int j = 0; j < 4; ++j) pk[j] = f2bf(hv[j]);
    *(u16x4*)((char*)hbuf + r * 128 + ((cb * 8) ^ ((r & 7) << 4))) = pk;
  }

  const float* Wg_[4] = {Wf, Wif, Wic, Wo};
  const float* bg_[4] = {bf_, bif_, bic_, bo_};
  const size_t probs_elems = (size_t)T_STEPS * BATCH * VSZ;

  if (wv < 4) {
    // ========== P-wave: minimal h-chain (r16 verbatim) ==========
    const int hcol = 16 * wv + lrow;

    bf16x8 fragWh[4][2];
#pragma unroll
    for (int g = 0; g < 4; ++g)
#pragma unroll
      for (int kf = 0; kf < 2; ++kf) {
        const float* p = Wg_[g] + hcol * ZSZ + ISZ + kf * 32 + 8 * lkg;
        bf16x8 f;
#pragma unroll
        for (int e = 0; e < 8; ++e) f[e] = (short)f2bf(p[e]);
        fragWh[g][kf] = f;
      }

    f32x4 cst = {0.f, 0.f, 0.f, 0.f}, hhv = {0.f, 0.f, 0.f, 0.f};
    if (lrow < MBLK)
      cst = *(const f32x4*)&c0[(b0 + lrow) * HSZ + 16 * wv + 4 * lkg];

    __builtin_amdgcn_s_setprio(1);
    __syncthreads();   // (B): X produced g[0], g[1]

    f32x4 acc[4];
    {
      const float* gs = &gbuf[0][wv][0];
#pragma unroll
      for (int g = 0; g < 4; ++g)
        acc[g] = *(const f32x4*)&gs[(g * 4 + lkg) * 64 + lrow * 4];
    }

    for (int t = 0; t < T_STEPS; ++t) {
      __builtin_amdgcn_s_barrier();
      asm volatile("" ::: "memory");

      const char* hbase = (const char*)hbuf + (t & 7) * 2048 + lrow * 128;
      const bf16x8 hB0 = *(const bf16x8*)(hbase + ((lkg * 16) ^ swz));
      const bf16x8 hB1 = *(const bf16x8*)(hbase + ((64 + lkg * 16) ^ swz));

      f32x4 cur[4];
#pragma unroll
      for (int g = 0; g < 4; ++g)
        cur[g] = __builtin_amdgcn_mfma_f32_16x16x32_bf16(fragWh[g][0], hB0, acc[g], 0, 0, 0);
#pragma unroll
      for (int g = 0; g < 4; ++g)
        cur[g] = __builtin_amdgcn_mfma_f32_16x16x32_bf16(fragWh[g][1], hB1, cur[g], 0, 0, 0);

      // preload next round's x-part acc (written by X >=1 barrier ago)
      {
        const float* gs = &gbuf[(t + 1) & 3][wv][0];
#pragma unroll
        for (int g = 0; g < 4; ++g)
          acc[g] = *(const f32x4*)&gs[(g * 4 + lkg) * 64 + lrow * 4];
      }

      // cell update: fully in-lane, lanes lrow<8
      if (lrow < MBLK) {
        u16x4 pk;
#pragma unroll
        for (int e = 0; e < 4; ++e) {
          const float fg = fsig(cur[0][e]);
          const float ig = fsig(cur[1][e]);
          const float cd = ftanh2(cur[2][e]);
          const float og = fsig(cur[3][e]);
          const float c  = cst[e] * fg + cd * ig;
          cst[e] = c;
          hhv[e] = ftanh2(c) * og;
          pk[e] = f2bf_hw(hhv[e]);
        }
        *(u16x4*)((char*)hbuf + ((t + 1) & 7) * 2048 + lrow * 128 +
                  ((32 * wv + 8 * lkg) ^ swz)) = pk;
      }

      asm volatile("s_waitcnt lgkmcnt(0)" ::: "memory");
    }

    __builtin_amdgcn_s_barrier();   // final (matches X/O epilogue)
    if (lrow < MBLK) {
      *(f32x4*)&out[probs_elems + (size_t)(b0 + lrow) * HSZ + 16 * wv + 4 * lkg] = hhv;
      *(f32x4*)&out[probs_elems + (size_t)BATCH * HSZ +
                    (size_t)(b0 + lrow) * HSZ + 16 * wv + 4 * lkg] = cst;
    }
  } else if (wv < 8) {
    // ========== X-wave: register-staged x pair-GEMM (no LDS x traffic) ======
    const int xw = wv - 4;
    const int hcolX = 16 * xw + lrow;
    const int prow = lrow & 7;

    bf16x8 fragWx[4][4];
#pragma unroll
    for (int g = 0; g < 4; ++g)
#pragma unroll
      for (int kf = 0; kf < 4; ++kf) {
        const float* p = Wg_[g] + hcolX * ZSZ + kf * 32 + 8 * lkg;
        bf16x8 f;
#pragma unroll
        for (int e = 0; e < 8; ++e) f[e] = (short)f2bf(p[e]);
        fragWx[g][kf] = f;
      }
    f32x4 biasV[4];
#pragma unroll
    for (int g = 0; g < 4; ++g)
      biasV[g] = *(const f32x4*)&bg_[g][16 * xw + 4 * lkg];

// load pair (T0, T0+1) into 8 f32x4: lane's tile = T0 + (lrow>>3)
#define XLOADP(T0, RA)                                                         \
    {                                                                          \
      const int tq = (T0) + (lrow >> 3);                                       \
      const int tt = (tq < T_STEPS) ? tq : T_STEPS - 1;                        \
      const float* xp = x + (size_t)tt * BATCH * ISZ +                         \
                        (size_t)(b0 + prow) * ISZ + 8 * lkg;                   \
      _Pragma("unroll")                                                        \
      for (int kf = 0; kf < 4; ++kf) {                                         \
        RA[2 * kf]     = *(const f32x4*)(xp + kf * 32);                        \
        RA[2 * kf + 1] = *(const f32x4*)(xp + kf * 32 + 4);                    \
      }                                                                        \
    }

// pair-GEMM from registers -> f32 gbuf slots GE (even tile) / GO (odd tile)
// (r16-verbatim gbuf addressing — known-good)
#define XPAIRR(RA, GE, GO)                                                     \
    {                                                                          \
      f32x4 xacc[4];                                                           \
      _Pragma("unroll")                                                        \
      for (int g = 0; g < 4; ++g) xacc[g] = biasV[g];                          \
      _Pragma("unroll")                                                        \
      for (int kf = 0; kf < 4; ++kf) {                                         \
        bf16x8 f;                                                              \
        _Pragma("unroll")                                                      \
        for (int j = 0; j < 4; ++j) {                                          \
          f[j]     = (short)f2bf_hw(RA[2 * kf][j]);                            \
          f[4 + j] = (short)f2bf_hw(RA[2 * kf + 1][j]);                        \
        }                                                                      \
        _Pragma("unroll")                                                      \
        for (int g = 0; g < 4; ++g)                                            \
          xacc[g] = __builtin_amdgcn_mfma_f32_16x16x32_bf16(                   \
              fragWx[g][kf], f, xacc[g], 0, 0, 0);                             \
      }                                                                        \
      float* gdst = (lrow & 8) ? &gbuf[GO][xw][0] : &gbuf[GE][xw][0];          \
      _Pragma("unroll")                                                        \
      for (int g = 0; g < 4; ++g)                                              \
        *(f32x4*)&gdst[(g * 4 + lkg) * 64 + prow * 4] = xacc[g];               \
    }

    // prologue: produce g[0], g[1]; leave pairs (2,3) and (4,5) in flight
    {
      f32x4 rC[8];
      XLOADP(0, rC)
      XPAIRR(rC, 0, 1)
    }
    f32x4 rA[8], rB[8];
    XLOADP(2, rA)
    XLOADP(4, rB)
    asm volatile("s_waitcnt lgkmcnt(0)" ::: "memory");
    __syncthreads();   // (B)

    for (int t = 0; t < T_STEPS; t += 4) {
      // round t: produce pair (t+2, t+3) from rA; refill rA <- (t+6, t+7)
      __builtin_amdgcn_s_barrier();
      asm volatile("" ::: "memory");
      XPAIRR(rA, (t + 2) & 3, (t + 3) & 3)
      XLOADP(t + 6, rA)
      asm volatile("s_waitcnt lgkmcnt(0)" ::: "memory");

      // round t+1: idle
      __builtin_amdgcn_s_barrier();
      asm volatile("" ::: "memory");

      // round t+2: produce pair (t+4, t+5) from rB; refill rB <- (t+8, t+9)
      __builtin_amdgcn_s_barrier();
      asm volatile("" ::: "memory");
      XPAIRR(rB, (t + 4) & 3, (t + 5) & 3)
      XLOADP(t + 8, rB)
      asm volatile("s_waitcnt lgkmcnt(0)" ::: "memory");

      // round t+3: idle
      __builtin_amdgcn_s_barrier();
      asm volatile("" ::: "memory");
    }
    __builtin_amdgcn_s_barrier();   // final
#undef XPAIRR
#undef XLOADP
  } else {
    // ========== O-wave: out-proj + softmax + probs store (r16 verbatim) ======
    const int o = wv - 8;

    bf16x8 fragWo[8][2];
#pragma unroll
    for (int rf = 0; rf < 8; ++rf)
#pragma unroll
      for (int kf = 0; kf < 2; ++kf) {
        const float* p = Wout + (16 * rf + lrow) * HSZ + kf * 32 + 8 * lkg;
        bf16x8 f;
#pragma unroll
        for (int e = 0; e < 8; ++e) f[e] = (short)f2bf(p[e]);
        fragWo[rf][kf] = f;
      }
    f32x4 boV[8];
#pragma unroll
    for (int rf = 0; rf < 8; ++rf) boV[rf] = *(const f32x4*)&bout_[16 * rf + 4 * lkg];

    __syncthreads();   // (B)

    f32x4 lac[8];
    bf16x8 hO0, hO1;
    float inv = 0.0f;

    for (int e = 0; e < 128; ++e) {
      const int tau = 4 * (e - 1) + 1 + o;
      const bool act = (e > 0);

      __builtin_amdgcn_s_barrier();
      asm volatile("" ::: "memory");
      if (act) {
        const char* hb = (const char*)hbuf + (tau & 7) * 2048 + lrow * 128;
        hO0 = *(const bf16x8*)(hb + ((lkg * 16) ^ swz));
        hO1 = *(const bf16x8*)(hb + ((64 + lkg * 16) ^ swz));
#pragma unroll
        for (int rf = 0; rf < 4; ++rf) {
          lac[rf] = boV[rf];
          lac[rf] = __builtin_amdgcn_mfma_f32_16x16x32_bf16(fragWo[rf][0], hO0, lac[rf], 0, 0, 0);
          lac[rf] = __builtin_amdgcn_mfma_f32_16x16x32_bf16(fragWo[rf][1], hO1, lac[rf], 0, 0, 0);
        }
      }

      __builtin_amdgcn_s_barrier();
      asm volatile("" ::: "memory");
      if (act) {
#pragma unroll
        for (int rf = 4; rf < 8; ++rf) {
          lac[rf] = boV[rf];
          lac[rf] = __builtin_amdgcn_mfma_f32_16x16x32_bf16(fragWo[rf][0], hO0, lac[rf], 0, 0, 0);
          lac[rf] = __builtin_amdgcn_mfma_f32_16x16x32_bf16(fragWo[rf][1], hO1, lac[rf], 0, 0, 0);
        }
      }

      __builtin_amdgcn_s_barrier();
      asm volatile("" ::: "memory");
      if (act) {
        float m = -1e30f;
#pragma unroll
        for (int rf = 0; rf < 8; ++rf)
#pragma unroll
          for (int e2 = 0; e2 < 4; ++e2) m = fmaxf(m, lac[rf][e2]);
        m = fmaxf(m, __shfl_xor(m, 16));
        m = fmaxf(m, __shfl_xor(m, 32));
        float s = 0.0f;
#pragma unroll
        for (int rf = 0; rf < 8; ++rf)
#pragma unroll
          for (int e2 = 0; e2 < 4; ++e2) {
            float p = __expf(lac[rf][e2] - m);
            lac[rf][e2] = p;
            s += p;
          }
        s += __shfl_xor(s, 16);
        s += __shfl_xor(s, 32);
        inv = 1.0f / s;
      }

      __builtin_amdgcn_s_barrier();
      asm volatile("" ::: "memory");
      if (act && lrow < MBLK) {
        float* orow = &out[(size_t)(tau - 1) * BATCH * VSZ +
                           (size_t)(b0 + lrow) * VSZ];
#pragma unroll
        for (int rf = 0; rf < 8; ++rf) {
          f32x4 pv = lac[rf] * inv;
          *(f32x4*)&orow[16 * rf + 4 * lkg] = pv;
        }
      }
    }

    __builtin_amdgcn_s_barrier();   // final
    {
      const int tau = T_STEPS - 3 + o;
      const char* hb = (const char*)hbuf + (tau & 7) * 2048 + lrow * 128;
      const bf16x8 ha = *(const bf16x8*)(hb + ((lkg * 16) ^ swz));
      const bf16x8 hbv = *(const bf16x8*)(hb + ((64 + lkg * 16) ^ swz));
#pragma unroll
      for (int rf = 0; rf < 8; ++rf) {
        lac[rf] = boV[rf];
        lac[rf] = __builtin_amdgcn_mfma_f32_16x16x32_bf16(fragWo[rf][0], ha, lac[rf], 0, 0, 0);
        lac[rf] = __builtin_amdgcn_mfma_f32_16x16x32_bf16(fragWo[rf][1], hbv, lac[rf], 0, 0, 0);
      }
      float m = -1e30f;
#pragma unroll
      for (int rf = 0; rf < 8; ++rf)
#pragma unroll
        for (int e2 = 0; e2 < 4; ++e2) m = fmaxf(m, lac[rf][e2]);
      m = fmaxf(m, __shfl_xor(m, 16));
      m = fmaxf(m, __shfl_xor(m, 32));
      float s = 0.0f;
#pragma unroll
      for (int rf = 0; rf < 8; ++rf)
#pragma unroll
        for (int e2 = 0; e2 < 4; ++e2) {
          float p = __expf(lac[rf][e2] - m);
          lac[rf][e2] = p;
          s += p;
        }
      s += __shfl_xor(s, 16);
      s += __shfl_xor(s, 32);
      inv = 1.0f / s;
      if (lrow < MBLK) {
        float* orow = &out[(size_t)(tau - 1) * BATCH * VSZ +
                           (size_t)(b0 + lrow) * VSZ];
#pragma unroll
        for (int rf = 0; rf < 8; ++rf) {
          f32x4 pv = lac[rf] * inv;
          *(f32x4*)&orow[16 * rf + 4 * lkg] = pv;
        }
      }
    }
  }
}

extern "C" void kernel_launch(void* const* d_in, const int* in_sizes, int n_in,
                              void* d_out, int out_size, void* d_ws, size_t ws_size,
                              hipStream_t stream) {
  const float* x    = (const float*)d_in[0];
  const float* h0   = (const float*)d_in[1];
  const float* c0   = (const float*)d_in[2];
  const float* Wf   = (const float*)d_in[3];
  const float* bf_  = (const float*)d_in[4];
  const float* Wif  = (const float*)d_in[5];
  const float* bif_ = (const float*)d_in[6];
  const float* Wic  = (const float*)d_in[7];
  const float* bic_ = (const float*)d_in[8];
  const float* Wo   = (const float*)d_in[9];
  const float* bo_  = (const float*)d_in[10];
  const float* Wout = (const float*)d_in[11];
  const float* bout = (const float*)d_in[12];
  float* out = (float*)d_out;

  hipLaunchKernelGGL(lstm_fused, dim3(BATCH / MBLK), dim3(ATHREADS), 0, stream,
                     x, h0, c0, Wf, bf_, Wif, bif_, Wic, bic_, Wo, bo_,
                     Wout, bout, out);
}